// Round 4
// baseline (629.135 us; speedup 1.0000x reference)
//
#include <hip/hip_runtime.h>
#include <hip/hip_bf16.h>
#include <hip/hip_cooperative_groups.h>

namespace cg = cooperative_groups;

#define NB     32
#define TLEN   4096
#define ENCH   512
#define ATTH   256
#define OUTD   80
#define SPKD   64
#define KW     31
#define ATTR   10

// ===========================================================================
// Cooperative single-dispatch kernel. Grid 640 x 256.
// P0: zero out | argmax | h1 matmul | cnt init      -> grid.sync
// P1: op matmul                                     -> grid.sync
// P2: bias matmul + spkr/speed                      -> grid.sync
// P3: band logits + atomic-counter softmax
// ws layouts (col-major [cols][32] for h1/op so both write & read coalesce)
// ===========================================================================
__global__ __launch_bounds__(256, 4) void coop_kernel(
    const float* __restrict__ input_enc, const float* __restrict__ input_dec,
    const float* __restrict__ pa,        const float* __restrict__ spkr_vec,
    const int*   __restrict__ lengths,   const float* __restrict__ speed,
    const float* __restrict__ W_enc,     const float* __restrict__ b_enc,
    const float* __restrict__ W_spkr,    const float* __restrict__ conv_w,
    const float* __restrict__ W_dec,     const float* __restrict__ W_speed,
    const float* __restrict__ Wp1,       const float* __restrict__ bp1,
    const float* __restrict__ Wp2,       const float* __restrict__ bp2,
    const float* __restrict__ W_proj,    float* __restrict__ out,
    int* __restrict__ ws_lohi,           int* __restrict__ ws_cnt,
    float* __restrict__ ws_h1,           float* __restrict__ ws_op,
    float* __restrict__ ws_bias,         float* __restrict__ ws_logits)
{
  const int b   = blockIdx.x;
  const int tid = threadIdx.x;
  __shared__ __align__(16) float smem[8192];   // 32 KB, aliased per phase
  cg::grid_group grid = cg::this_grid();

  // ------------------------- P0 -------------------------
  if (b < 64) {
    // h1[m, c0..c0+15] = relu(dec_in @ Wp1 + bp1), batched over all 32 m
    const int c0 = b * 16;
    float* s_dec = smem;            // [32][145] padded (stride 145: conflict-free)
    float* s_w1  = smem + 4640;     // [144][16]
    for (int idx = tid; idx < 4608; idx += 256) {
      int m = idx / 144, r = idx - m * 144;
      s_dec[m * 145 + r] = (r < OUTD) ? input_dec[m * OUTD + r]
                                      : spkr_vec[m * SPKD + (r - OUTD)];
    }
    for (int idx = tid; idx < 2304; idx += 256) {
      int i = idx >> 4, c = idx & 15;
      s_w1[idx] = Wp1[i * 1024 + c0 + c];
    }
    __syncthreads();
    const int m = tid & 31, q = tid >> 5;       // 2 cols per thread: q, q+8
    float a0 = 0.f, a1 = 0.f;
    #pragma unroll 8
    for (int i = 0; i < 144; i++) {
      float d = s_dec[m * 145 + i];
      a0 = fmaf(d, s_w1[i * 16 + q],     a0);
      a1 = fmaf(d, s_w1[i * 16 + q + 8], a1);
    }
    ws_h1[(c0 + q)     * 32 + m] = fmaxf(a0 + bp1[c0 + q],     0.f);
    ws_h1[(c0 + q + 8) * 32 + m] = fmaxf(a1 + bp1[c0 + q + 8], 0.f);
  } else if (b < 96) {
    // argmax(prev_attention[n,:]) -> band [lo,hi]
    const int n = b - 64;
    float* s_v = smem;
    int*   s_i = (int*)(smem + 256);
    const float* p = pa + (size_t)n * TLEN;
    float bv = -1.f; int bi = 0;
    #pragma unroll
    for (int k = 0; k < 16; k++) {
      int t = tid + k * 256;         // increasing t: strict > keeps first index
      float v = p[t];
      if (v > bv) { bv = v; bi = t; }
    }
    s_v[tid] = bv; s_i[tid] = bi;
    __syncthreads();
    for (int s = 128; s > 0; s >>= 1) {
      if (tid < s) {
        float ov = s_v[tid + s]; int oi = s_i[tid + s];
        if (ov > s_v[tid] || (ov == s_v[tid] && oi < s_i[tid])) {
          s_v[tid] = ov; s_i[tid] = oi;
        }
      }
      __syncthreads();
    }
    if (tid == 0) {
      int mi = s_i[0];
      ws_lohi[n * 2]     = max(mi - (ATTR - 1), 0);
      ws_lohi[n * 2 + 1] = min(mi + (ATTR - 1), lengths[n] - 1);
    }
  } else if (b < 224) {
    // zero entire out (harness poisons with 0xAA): 128 blocks x 256 float4
    ((float4*)out)[(b - 96) * 256 + tid] = make_float4(0.f, 0.f, 0.f, 0.f);
  } else if (b == 224) {
    if (tid < NB) ws_cnt[tid] = 0;   // softmax completion counters
  }
  grid.sync();

  // ------------------------- P1: op = relu(h1 @ Wp2 + bp2) -------------------------
  if (b < 128) {
    const int c0 = b * 4;
    float* s_w2 = smem;           // [1024][4]
    float* s_hh = smem + 4096;    // [128][32] k-tile of h1 (col-major)
    for (int idx = tid; idx < 4096; idx += 256) {
      int r = idx >> 2, c = idx & 3;
      s_w2[idx] = Wp2[r * 512 + c0 + c];
    }
    const int m = tid & 31, q = tid >> 5, c = q & 3, ks = q >> 2;
    float acc = 0.f;
    for (int kb = 0; kb < 8; kb++) {
      if (kb) __syncthreads();                 // previous tile fully consumed
      for (int idx = tid; idx < 4096; idx += 256)
        s_hh[idx] = ws_h1[kb * 4096 + idx];    // coalesced (col-major)
      __syncthreads();                         // also covers s_w2 on kb==0
      const int ib = ks * 64;
      #pragma unroll 8
      for (int i2 = 0; i2 < 64; i2++) {
        int i = ib + i2;
        acc = fmaf(s_hh[i * 32 + m], s_w2[(kb * 128 + i) * 4 + c], acc);
      }
    }
    __syncthreads();
    smem[tid] = acc;                           // s_red aliases s_w2 (all reads done)
    __syncthreads();
    if (ks == 0) {                             // tid < 128
      float tot = smem[tid] + smem[tid + 128];
      ws_op[(c0 + c) * 32 + m] = fmaxf(tot + bp2[c0 + c], 0.f);
    }
  }
  grid.sync();

  // ------------- P2: bias = op @ W_dec + softsign(spkr@W_spkr) + speed*W_speed -------------
  if (b < 128) {
    const int c0 = b * 2;
    float* s_wd  = smem;          // [512][2]
    float* s_red = smem + 2048;
    for (int idx = tid; idx < 1024; idx += 256) {
      int r = idx >> 1, cc = idx & 1;
      s_wd[idx] = W_dec[r * 256 + c0 + cc];
    }
    __syncthreads();
    const int m = tid & 31, q = tid >> 5, c = q & 1, ks = q >> 1;  // 4-way K-split
    float acc = 0.f;
    const int kb = ks * 128;
    #pragma unroll 8
    for (int i2 = 0; i2 < 128; i2++) {
      int k = kb + i2;
      acc = fmaf(ws_op[k * 32 + m], s_wd[k * 2 + c], acc);  // coalesced global
    }
    s_red[tid] = acc;
    __syncthreads();
    if (q < 2) {                                // (c=q, n=m), 64 threads
      float tot = s_red[(0 * 2 + c) * 32 + m] + s_red[(1 * 2 + c) * 32 + m]
                + s_red[(2 * 2 + c) * 32 + m] + s_red[(3 * 2 + c) * 32 + m];
      float sp = 0.f;
      #pragma unroll 8
      for (int i = 0; i < SPKD; i++)
        sp = fmaf(spkr_vec[m * SPKD + i], W_spkr[i * 256 + c0 + c], sp);
      sp = sp / (1.f + fabsf(sp));
      ws_bias[m * 256 + c0 + c] = tot + sp + speed[m] * W_speed[c0 + c];
    }
  }
  grid.sync();

  // ------------------------- P3: band logits + atomic softmax -------------------------
  {
    const int n = b / 20;
    const int j = b - n * 20;
    const int lo = ws_lohi[n * 2], hi = ws_lohi[n * 2 + 1];
    const int t  = lo + j;
    const bool valid = (t <= hi);               // block-uniform

    float* s_enc  = smem;                       // 512
    float* s_red  = smem + 512;                 // 1024
    float* s_pa   = smem + 1536;                // 31
    float* s_part = smem + 1568;                // 4
    int*   s_old  = (int*)(smem + 1572);

    if (valid) {
      if (tid < 128)
        ((float4*)s_enc)[tid] =
            ((const float4*)(input_enc + ((size_t)n * TLEN + t) * ENCH))[tid];
      else if (tid < 128 + KW) {
        int idx = t - (KW / 2) + (tid - 128);
        s_pa[tid - 128] = (idx >= 0 && idx < TLEN) ? pa[(size_t)n * TLEN + idx] : 0.f;
      }
      __syncthreads();
      // 4-way K-split GEMV, float4 W_enc loads (proven R3 structure)
      const int sl = tid >> 6, l4 = tid & 63;
      const float4* W4 = (const float4*)W_enc;
      float4 a4 = make_float4(0.f, 0.f, 0.f, 0.f);
      const int i0 = sl * 128;
      #pragma unroll 8
      for (int i = i0; i < i0 + 128; i++) {
        float e  = s_enc[i];
        float4 w = W4[i * 64 + l4];
        a4.x = fmaf(e, w.x, a4.x);
        a4.y = fmaf(e, w.y, a4.y);
        a4.z = fmaf(e, w.z, a4.z);
        a4.w = fmaf(e, w.w, a4.w);
      }
      *(float4*)(s_red + sl * 256 + l4 * 4) = a4;
      __syncthreads();
      const int c = tid;
      float y = s_red[c] + s_red[256 + c] + s_red[512 + c] + s_red[768 + c];
      float cv = 0.f;
      #pragma unroll
      for (int k = 0; k < KW; k++)
        cv = fmaf(s_pa[k], conv_w[c * KW + k], cv);
      float ss = y + b_enc[c];
      ss = ss / (1.f + fabsf(ss));
      float v = tanhf(ss + ws_bias[n * 256 + c] + cv) * W_proj[c];
      #pragma unroll
      for (int off = 32; off > 0; off >>= 1) v += __shfl_down(v, off);
      if ((tid & 63) == 0) s_part[tid >> 6] = v;
      __syncthreads();
      if (tid == 0)
        ws_logits[n * 20 + j] = s_part[0] + s_part[1] + s_part[2] + s_part[3];
    } else {
      if (tid == 0) ws_logits[n * 20 + j] = -__builtin_inff();
    }

    // completion protocol: last of the 20 blocks for batch n does the softmax
    if (tid == 0) {
      __threadfence();                          // release logit store
      *s_old = atomicAdd(&ws_cnt[n], 1);        // device-scope
    }
    __syncthreads();
    if (*s_old == 19 && tid < 64) {
      __threadfence();                          // acquire others' logits
      float l = (tid < 20) ? ws_logits[n * 20 + tid] : -__builtin_inff();
      float m2 = l;
      #pragma unroll
      for (int off = 32; off > 0; off >>= 1) m2 = fmaxf(m2, __shfl_down(m2, off));
      m2 = __shfl(m2, 0);
      float e = __expf(l - m2);                 // -inf -> 0
      float s = e;
      #pragma unroll
      for (int off = 32; off > 0; off >>= 1) s += __shfl_down(s, off);
      s = __shfl(s, 0);
      int tt = lo + tid;
      if (tid < 20 && tt <= hi)
        out[(size_t)n * TLEN + tt] = e / s;
    }
  }
}

// ===========================================================================
// Fallback path (exact R3 structure) if cooperative launch is rejected.
// ===========================================================================
__global__ __launch_bounds__(1024) void prep_kernel(
    const float* __restrict__ pa, const float* __restrict__ input_dec,
    const float* __restrict__ spkr_vec, const float* __restrict__ speed,
    const float* __restrict__ Wp1, const float* __restrict__ bp1,
    const float* __restrict__ Wp2, const float* __restrict__ bp2,
    const float* __restrict__ W_dec, const float* __restrict__ W_spkr,
    const float* __restrict__ W_speed, const int* __restrict__ lengths,
    float* __restrict__ out, int* __restrict__ ws_idx, float* __restrict__ ws_bias)
{
  const int n = blockIdx.x, tid = threadIdx.x;
  __shared__ float s_dec[144];
  __shared__ float s_h1[1024];
  __shared__ float s_op[512];
  __shared__ __align__(16) float s_red[8 * 512];
  __shared__ float s_av[1024];
  __shared__ int   s_ai[1024];

  ((float4*)(out + (size_t)n * TLEN))[tid] = make_float4(0.f, 0.f, 0.f, 0.f);
  if (tid < OUTD)      s_dec[tid] = input_dec[n * OUTD + tid];
  else if (tid < 144)  s_dec[tid] = spkr_vec[n * SPKD + (tid - OUTD)];
  {
    const float* p = pa + (size_t)n * TLEN;
    float bv = -1.f; int bi = 0;
    #pragma unroll
    for (int k = 0; k < TLEN / 1024; k++) {
      int t = tid + k * 1024;
      float v = p[t];
      if (v > bv) { bv = v; bi = t; }
    }
    s_av[tid] = bv; s_ai[tid] = bi;
    __syncthreads();
    for (int s = 512; s > 0; s >>= 1) {
      if (tid < s) {
        float ov = s_av[tid + s]; int oi = s_ai[tid + s];
        float mv = s_av[tid];     int mi = s_ai[tid];
        if (ov > mv || (ov == mv && oi < mi)) { s_av[tid] = ov; s_ai[tid] = oi; }
      }
      __syncthreads();
    }
    if (tid == 0) {
      int mi = s_ai[0];
      ws_idx[n * 2]     = max(mi - (ATTR - 1), 0);
      ws_idx[n * 2 + 1] = min(mi + (ATTR - 1), lengths[n] - 1);
    }
  }
  {
    float acc = bp1[tid];
    #pragma unroll 4
    for (int i = 0; i < 144; i++) acc = fmaf(s_dec[i], Wp1[i * 1024 + tid], acc);
    s_h1[tid] = fmaxf(acc, 0.f);
  }
  __syncthreads();
  {
    const int g = tid & 127, sl = tid >> 7;
    const int k0 = g * 4;
    float4 acc = make_float4(0.f, 0.f, 0.f, 0.f);
    for (int j = sl; j < 1024; j += 8) {
      float hv = s_h1[j];
      float4 w = *(const float4*)(Wp2 + (size_t)j * 512 + k0);
      acc.x = fmaf(hv, w.x, acc.x); acc.y = fmaf(hv, w.y, acc.y);
      acc.z = fmaf(hv, w.z, acc.z); acc.w = fmaf(hv, w.w, acc.w);
    }
    *(float4*)(s_red + sl * 512 + k0) = acc;
    __syncthreads();
    if (tid < 512) {
      float v = bp2[tid];
      #pragma unroll
      for (int s2 = 0; s2 < 8; s2++) v += s_red[s2 * 512 + tid];
      s_op[tid] = fmaxf(v, 0.f);
    }
    __syncthreads();
  }
  {
    const int c = tid & 255, sl = tid >> 8;
    float acc = 0.f;
    const int kb = sl * 128;
    #pragma unroll 4
    for (int k = kb; k < kb + 128; k++) acc = fmaf(s_op[k], W_dec[k * 256 + c], acc);
    s_red[sl * 256 + c] = acc;
    __syncthreads();
    if (tid < 256) {
      float b2 = s_red[tid] + s_red[256 + tid] + s_red[512 + tid] + s_red[768 + tid];
      float sp = 0.f;
      #pragma unroll 4
      for (int i = 0; i < 64; i++) sp = fmaf(s_dec[OUTD + i], W_spkr[i * 256 + tid], sp);
      sp = sp / (1.f + fabsf(sp));
      ws_bias[n * 256 + tid] = b2 + sp + speed[n] * W_speed[tid];
    }
  }
}

__global__ __launch_bounds__(256) void band_kernel(
    const float* __restrict__ input_enc, const float* __restrict__ pa,
    const float* __restrict__ W_enc, const float* __restrict__ b_enc,
    const float* __restrict__ conv_w, const float* __restrict__ W_proj,
    const int* __restrict__ ws_idx, const float* __restrict__ ws_bias,
    float* __restrict__ ws_logits)
{
  const int n = blockIdx.x, j = blockIdx.y, tid = threadIdx.x;
  const int lo = ws_idx[n * 2], hi = ws_idx[n * 2 + 1];
  const int t = lo + j;
  if (t > hi) { if (tid == 0) ws_logits[n * 20 + j] = -__builtin_inff(); return; }

  __shared__ __align__(16) float s_enc[ENCH];
  __shared__ float s_pa[KW];
  __shared__ __align__(16) float s_red[4 * 256];
  __shared__ float s_cw[ATTH * KW];
  __shared__ float s_part[4];

  for (int k2 = tid; k2 < ATTH * KW; k2 += 256) s_cw[k2] = conv_w[k2];
  if (tid < 128)
    ((float4*)s_enc)[tid] = ((const float4*)(input_enc + ((size_t)n * TLEN + t) * ENCH))[tid];
  else if (tid < 128 + KW) {
    int idx = t - (KW / 2) + (tid - 128);
    s_pa[tid - 128] = (idx >= 0 && idx < TLEN) ? pa[(size_t)n * TLEN + idx] : 0.f;
  }
  __syncthreads();
  {
    const int sl = tid >> 6, l4 = tid & 63;
    const float4* W4 = (const float4*)W_enc;
    float4 acc = make_float4(0.f, 0.f, 0.f, 0.f);
    const int i0 = sl * 128;
    #pragma unroll 8
    for (int i = i0; i < i0 + 128; i++) {
      float e = s_enc[i];
      float4 w = W4[i * 64 + l4];
      acc.x = fmaf(e, w.x, acc.x); acc.y = fmaf(e, w.y, acc.y);
      acc.z = fmaf(e, w.z, acc.z); acc.w = fmaf(e, w.w, acc.w);
    }
    *(float4*)(s_red + sl * 256 + l4 * 4) = acc;
  }
  __syncthreads();
  {
    const int c = tid;
    float y = s_red[c] + s_red[256 + c] + s_red[512 + c] + s_red[768 + c];
    float cv = 0.f;
    #pragma unroll
    for (int k = 0; k < KW; k++) cv = fmaf(s_pa[k], s_cw[c * KW + k], cv);
    float ss = y + b_enc[c];
    ss = ss / (1.f + fabsf(ss));
    float v = tanhf(ss + ws_bias[n * 256 + c] + cv) * W_proj[c];
    #pragma unroll
    for (int off = 32; off > 0; off >>= 1) v += __shfl_down(v, off);
    if ((tid & 63) == 0) s_part[tid >> 6] = v;
  }
  __syncthreads();
  if (tid == 0)
    ws_logits[n * 20 + j] = s_part[0] + s_part[1] + s_part[2] + s_part[3];
}

__global__ __launch_bounds__(64) void softmax_kernel(
    const float* __restrict__ ws_logits, const int* __restrict__ ws_idx,
    float* __restrict__ out)
{
  const int n = blockIdx.x, tid = threadIdx.x;
  const int lo = ws_idx[n * 2], hi = ws_idx[n * 2 + 1];
  float l = (tid < 20) ? ws_logits[n * 20 + tid] : -__builtin_inff();
  float m = l;
  #pragma unroll
  for (int off = 32; off > 0; off >>= 1) m = fmaxf(m, __shfl_down(m, off));
  m = __shfl(m, 0);
  float e = __expf(l - m);
  float s = e;
  #pragma unroll
  for (int off = 32; off > 0; off >>= 1) s += __shfl_down(s, off);
  s = __shfl(s, 0);
  int t = lo + tid;
  if (tid < 20 && t <= hi) out[(size_t)n * TLEN + t] = e / s;
}

// ---------------------------------------------------------------------------
extern "C" void kernel_launch(void* const* d_in, const int* in_sizes, int n_in,
                              void* d_out, int out_size, void* d_ws, size_t ws_size,
                              hipStream_t stream) {
  const float* input_enc = (const float*)d_in[0];
  const float* input_dec = (const float*)d_in[1];
  const float* pa        = (const float*)d_in[2];
  const float* spkr_vec  = (const float*)d_in[3];
  const int*   lengths   = (const int*)  d_in[4];
  const float* speed     = (const float*)d_in[5];
  const float* W_enc     = (const float*)d_in[6];
  const float* b_enc     = (const float*)d_in[7];
  const float* W_spkr    = (const float*)d_in[8];
  const float* conv_w    = (const float*)d_in[9];
  const float* W_dec     = (const float*)d_in[10];
  const float* W_speed   = (const float*)d_in[11];
  const float* Wp1       = (const float*)d_in[12];
  const float* bp1       = (const float*)d_in[13];
  const float* Wp2       = (const float*)d_in[14];
  const float* bp2       = (const float*)d_in[15];
  const float* W_proj    = (const float*)d_in[16];
  // d_in[17] = b_proj — cancels in the softmax, unused.

  float* out = (float*)d_out;

  // coop-kernel workspace layout
  int*   ws_lohi   = (int*)d_ws;                                  // [32,2]
  int*   ws_cnt    = (int*)((char*)d_ws + 256);                   // [32]
  float* ws_h1     = (float*)((char*)d_ws + 1024);                // [1024][32]
  float* ws_op     = (float*)((char*)d_ws + 1024 + 131072);       // [512][32]
  float* ws_bias   = (float*)((char*)d_ws + 1024 + 131072 + 65536);   // [32,256]
  float* ws_logits = (float*)((char*)d_ws + 1024 + 131072 + 65536 + 32768); // [32,20]

  void* args[] = {
    (void*)&input_enc, (void*)&input_dec, (void*)&pa, (void*)&spkr_vec,
    (void*)&lengths, (void*)&speed, (void*)&W_enc, (void*)&b_enc,
    (void*)&W_spkr, (void*)&conv_w, (void*)&W_dec, (void*)&W_speed,
    (void*)&Wp1, (void*)&bp1, (void*)&Wp2, (void*)&bp2, (void*)&W_proj,
    (void*)&out, (void*)&ws_lohi, (void*)&ws_cnt, (void*)&ws_h1,
    (void*)&ws_op, (void*)&ws_bias, (void*)&ws_logits
  };
  hipError_t err = hipLaunchCooperativeKernel((const void*)coop_kernel,
                                              dim3(NB * 20), dim3(256),
                                              args, 0, stream);
  if (err != hipSuccess) {
    // fallback: proven R3 three-kernel path (own ws layout, disjoint use)
    int*   f_idx    = (int*)d_ws;
    float* f_bias   = (float*)((char*)d_ws + 256);
    float* f_logits = (float*)((char*)d_ws + 256 + NB * 256 * 4);
    hipLaunchKernelGGL(prep_kernel, dim3(NB), dim3(1024), 0, stream,
                       pa, input_dec, spkr_vec, speed, Wp1, bp1, Wp2, bp2,
                       W_dec, W_spkr, W_speed, lengths, out, f_idx, f_bias);
    hipLaunchKernelGGL(band_kernel, dim3(NB, 20), dim3(256), 0, stream,
                       input_enc, pa, W_enc, b_enc, conv_w, W_proj,
                       f_idx, f_bias, f_logits);
    hipLaunchKernelGGL(softmax_kernel, dim3(NB), dim3(64), 0, stream,
                       f_logits, f_idx, out);
  }
}